// Round 1
// 1081.129 us; speedup vs baseline: 1.1206x; 1.1206x over previous
//
#include <hip/hip_runtime.h>
#include <stdint.h>

#define B_ 4
#define QLEN_ 512
#define HID_ 4096
#define NH_ 32
#define NKV_ 8
#define HD_ 128
#define PREV_ 1016
#define TOTLEN_ 1528
#define KVLEN_ 1536
#define PREV_PAGES_ 64
#define NEW_PAGES_ 32
#define TOT_PAGES_ 96
#define MAXP_ 2048

typedef unsigned short u16;
typedef __attribute__((ext_vector_type(8))) short short8;
typedef __attribute__((ext_vector_type(4))) float f32x4;

__device__ __forceinline__ u16 f2bf(float x) {
  unsigned u = __float_as_uint(x);
  u += 0x7fffu + ((u >> 16) & 1u);
  return (u16)(u >> 16);
}

__device__ __forceinline__ unsigned cvt_pk_bf16(float lo, float hi) {
  unsigned r;
  asm("v_cvt_pk_bf16_f32 %0, %1, %2" : "=v"(r) : "v"(lo), "v"(hi));
  return r;
}

// ---------------- fp32 -> bf16 convert ----------------
__global__ void conv_bf16(const float* __restrict__ in, u16* __restrict__ out, int n8) {
  int i = blockIdx.x * 256 + threadIdx.x;
  if (i >= n8) return;
  size_t base = (size_t)i * 8;
  float4 a = *(const float4*)(in + base);
  float4 b = *(const float4*)(in + base + 4);
  union { u16 u[8]; short8 v; } r;
  r.u[0] = f2bf(a.x); r.u[1] = f2bf(a.y); r.u[2] = f2bf(a.z); r.u[3] = f2bf(a.w);
  r.u[4] = f2bf(b.x); r.u[5] = f2bf(b.y); r.u[6] = f2bf(b.z); r.u[7] = f2bf(b.w);
  *(short8*)(out + base) = r.v;
}

// ---------------- page allocator / int outputs ----------------
__global__ void page_setup(const int* __restrict__ kv_indptr, const int* __restrict__ kv_indices,
                           float* __restrict__ out_ints, int* __restrict__ aps) {
  __shared__ unsigned char used[MAXP_];
  __shared__ int offs[256];
  __shared__ int avail[B_ * NEW_PAGES_];
  int tid = threadIdx.x;
  for (int j = tid; j < MAXP_; j += 256) used[j] = 0;
  __syncthreads();
  for (int j = tid; j < B_ * PREV_PAGES_; j += 256) used[kv_indices[j]] = 1;
  __syncthreads();
  int cnt = 0;
  for (int i = 0; i < 8; i++) cnt += 1 - (int)used[tid * 8 + i];
  offs[tid] = cnt;
  __syncthreads();
  if (tid == 0) {
    int run = 0;
    for (int i = 0; i < 256; i++) { int c = offs[i]; offs[i] = run; run += c; }
  }
  __syncthreads();
  int run = offs[tid];
  for (int i = 0; i < 8; i++) {
    int p = tid * 8 + i;
    if (!used[p]) { if (run < B_ * NEW_PAGES_) avail[run] = p; run++; }
  }
  __syncthreads();
  if (tid < B_ + 1) out_ints[tid] = (float)(tid * TOT_PAGES_);
  if (tid < B_) out_ints[B_ + 1 + B_ * TOT_PAGES_ + tid] = 8.0f;  // (8+512-1)%16+1
  for (int j = tid; j < B_ * TOT_PAGES_; j += 256) {
    int b = j / TOT_PAGES_, r = j % TOT_PAGES_;
    int v = (r < PREV_PAGES_) ? kv_indices[b * PREV_PAGES_ + r] : avail[b * NEW_PAGES_ + (r - PREV_PAGES_)];
    out_ints[B_ + 1 + j] = (float)v;
  }
  for (int j = tid; j < B_ * 33; j += 256) {
    int b = j / 33, r = j % 33;
    aps[j] = (r == 0) ? kv_indices[kv_indptr[b + 1] - 1] : avail[b * NEW_PAGES_ + r - 1];
  }
}

// ---------------- GEMM: C[M,N] = A[M,K] * B[N,K]^T  (bf16 in, fp32 out) ----------------
__device__ __forceinline__ void async16(const u16* g, u16* l) {
  __builtin_amdgcn_global_load_lds((const __attribute__((address_space(1))) unsigned int*)g,
                                   (__attribute__((address_space(3))) unsigned int*)l, 16, 0, 0);
}

__global__ __launch_bounds__(256) void gemm_bt(const u16* __restrict__ A, const u16* __restrict__ Bm,
                                               float* __restrict__ C, int M, int N, int K) {
  __shared__ u16 a_sm[4096];  // 512 chunks of 16B, k-major with XOR swizzle
  __shared__ u16 b_sm[4096];
  const int tid = threadIdx.x;
  const int wave = tid >> 6, lane = tid & 63;
  const int quad = lane >> 4, l16 = lane & 15;
  const int wm = wave & 1, wn = wave >> 1;
  const size_t row0 = (size_t)blockIdx.y * 128, col0 = (size_t)blockIdx.x * 128;

  f32x4 zero4 = {0.f, 0.f, 0.f, 0.f};
  f32x4 acc[4][4];
#pragma unroll
  for (int i = 0; i < 4; i++)
#pragma unroll
    for (int j = 0; j < 4; j++) acc[i][j] = zero4;

  size_t aoffs[2], boffs[2];
  u16 *albase[2], *blbase[2];
#pragma unroll
  for (int i = 0; i < 2; i++) {
    int p = wave + i * 4;
    int c = p * 64 + lane;
    int r = c >> 2;
    int q = (c & 3) ^ ((r >> 1) & 3);  // XOR swizzle: coalesced global, 2-way LDS frag reads
    aoffs[i] = (row0 + r) * (size_t)K + q * 8;
    boffs[i] = (col0 + r) * (size_t)K + q * 8;
    albase[i] = a_sm + p * 512;
    blbase[i] = b_sm + p * 512;
  }

  for (int k0 = 0; k0 < K; k0 += 32) {
    __syncthreads();
#pragma unroll
    for (int i = 0; i < 2; i++) {
      async16(A + aoffs[i] + k0, albase[i]);
      async16(Bm + boffs[i] + k0, blbase[i]);
    }
    __syncthreads();
    short8 af[4];
#pragma unroll
    for (int mt = 0; mt < 4; mt++) {
      int row = wm * 64 + mt * 16 + l16;
      int idx = row * 4 + (quad ^ ((row >> 1) & 3));
      af[mt] = *(const short8*)&a_sm[idx * 8];
    }
#pragma unroll
    for (int nt = 0; nt < 4; nt++) {
      int col = wn * 64 + nt * 16 + l16;
      int idx = col * 4 + (quad ^ ((col >> 1) & 3));
      short8 bf = *(const short8*)&b_sm[idx * 8];
#pragma unroll
      for (int mt = 0; mt < 4; mt++)
        acc[mt][nt] = __builtin_amdgcn_mfma_f32_16x16x32_bf16(af[mt], bf, acc[mt][nt], 0, 0, 0);
    }
  }
#pragma unroll
  for (int mt = 0; mt < 4; mt++)
#pragma unroll
    for (int nt = 0; nt < 4; nt++) {
      size_t col = col0 + wn * 64 + nt * 16 + l16;
#pragma unroll
      for (int r = 0; r < 4; r++) {
        size_t row = row0 + wm * 64 + mt * 16 + quad * 4 + r;
        C[row * N + col] = acc[mt][nt][r];
      }
    }
}

// ---------------- scatter new K/V into paged output (kvf = [2048 tok][2048], K cols 0-1023, V 1024-2047) ----------------
__global__ void scatter_kv(const float* __restrict__ kvf, const int* __restrict__ aps,
                           float* __restrict__ outp) {
  int idx = blockIdx.x * 256 + threadIdx.x;  // 1,048,576 threads, 4 floats each
  int which = idx >> 19;
  int e4 = idx & 524287;
  size_t e = (size_t)e4 * 4;
  int bt = (int)(e >> 10);
  int b = bt >> 9, t = bt & 511;
  int c = (int)(e & 1023);
  int page = aps[b * 33 + ((8 + t) >> 4)];
  int slot = (8 + t) & 15;
  size_t dst = (((size_t)page * 2 + which) * 16 + slot) * 1024 + c;
  size_t src = (size_t)bt * 2048 + which * 1024 + c;
  *(float4*)(outp + dst) = *(const float4*)(kvf + src);
}

// ---------------- build roped bf16 K, contiguous [b*8+kvh][kv][128] ----------------
__global__ void build_kc(const float* __restrict__ paged, const float* __restrict__ kvf,
                         const int* __restrict__ kv_indices, u16* __restrict__ Kc) {
  int gid = blockIdx.x * 256 + threadIdx.x;  // 4*8*1536*64
  int d2 = gid & 63;
  int rest = gid >> 6;
  int kpos = rest % KVLEN_;
  int bh = rest / KVLEN_;
  float x1 = 0.f, x2 = 0.f;
  if (kpos < PREV_) {
    int page = kv_indices[(bh >> 3) * PREV_PAGES_ + (kpos >> 4)];
    size_t base = (((size_t)page * 2) * 16 + (kpos & 15)) * 1024 + (bh & 7) * 128;
    x1 = paged[base + d2]; x2 = paged[base + d2 + 64];
  } else if (kpos < TOTLEN_) {
    size_t base = ((size_t)(bh >> 3) * 512 + (kpos - PREV_)) * 2048 + (bh & 7) * 128;
    x1 = kvf[base + d2]; x2 = kvf[base + d2 + 64];
  }
  float inv = exp2f((float)d2 * -0.20762050593046014f);  // 10000^(-d2/64)
  float ang = (float)kpos * inv;
  float s, c;
  sincosf(ang, &s, &c);
  size_t ob = ((size_t)bh * KVLEN_ + kpos) * 128;
  Kc[ob + d2] = f2bf(x1 * c - x2 * s);
  Kc[ob + d2 + 64] = f2bf(x2 * c + x1 * s);
}

// ---------------- build transposed bf16 V: [b*8+kvh][hd=128][kv=1536] ----------------
__global__ void build_vt(const float* __restrict__ paged, const float* __restrict__ kvf,
                         const int* __restrict__ kv_indices, u16* __restrict__ Vt) {
  __shared__ float tile[64][129];
  int bx = blockIdx.x;  // 4*8*24
  int tk = bx % 24;
  int bh = bx / 24;
  int tid = threadIdx.x;
  for (int i = 0; i < 32; i++) {
    int e = tid + i * 256;
    int r = e >> 7, d = e & 127;
    int kpos = tk * 64 + r;
    float val = 0.f;
    if (kpos < PREV_) {
      int page = kv_indices[(bh >> 3) * PREV_PAGES_ + (kpos >> 4)];
      val = paged[(((size_t)page * 2 + 1) * 16 + (kpos & 15)) * 1024 + (bh & 7) * 128 + d];
    } else if (kpos < TOTLEN_) {
      val = kvf[((size_t)(bh >> 3) * 512 + (kpos - PREV_)) * 2048 + 1024 + (bh & 7) * 128 + d];
    }
    tile[r][d] = val;
  }
  __syncthreads();
  for (int i = 0; i < 32; i++) {
    int e = tid + i * 256;
    int d = e >> 6, kp = e & 63;
    Vt[((size_t)bh * 128 + d) * KVLEN_ + tk * 64 + kp] = f2bf(tile[kp][d]);
  }
}

// ---------------- fused flash attention (swapped-operand S^T/O^T formulation) ----------------
// S^T = mfma(K_frag, Q_frag): per-lane col q = l16 -> lane-local softmax row.
// O^T = mfma(V^T_frag, P^T_frag); epilogue transposes via retired k_sm.
__global__ __launch_bounds__(256, 3) void flash_attn(const float* __restrict__ qf, const u16* __restrict__ Kc,
                                                     const u16* __restrict__ Vt, u16* __restrict__ Obuf) {
  __shared__ u16 qp_sm[64 * 136];  // Q tile in prologue; per-wave P^T slices in main loop
  __shared__ u16 k_sm[64 * 136];   // K tile; O transpose scratch in epilogue
  __shared__ u16 v_sm[128 * 72];   // V^T tile
  const int qb = blockIdx.x, h = blockIdx.y, b = blockIdx.z;
  const int kvh = h >> 2;
  const int tid = threadIdx.x, wave = tid >> 6, lane = tid & 63;
  const int quad = lane >> 4, l16 = lane & 15;

  // ---- fused RoPE+scale Q stage: q_f32 [tok][4096] -> qp_sm [64][136] bf16 ----
  {
    const float scale = 0.08838834764831845f;  // 1/sqrt(128)
#pragma unroll
    for (int i = 0; i < 16; i++) {
      int e = i * 256 + tid;  // coalesced: consecutive lanes -> consecutive d2
      int r = e >> 6, d2 = e & 63;
      size_t base = ((size_t)(b * 512 + qb * 64 + r)) * 4096 + h * 128;
      float x1 = qf[base + d2], x2 = qf[base + d2 + 64];
      float inv = exp2f((float)d2 * -0.20762050593046014f);
      float ang = (float)(PREV_ + qb * 64 + r) * inv;
      float s, c;
      sincosf(ang, &s, &c);
      qp_sm[r * 136 + d2] = f2bf((x1 * c - x2 * s) * scale);
      qp_sm[r * 136 + d2 + 64] = f2bf((x2 * c + x1 * s) * scale);
    }
  }
  __syncthreads();
  short8 aq[4];
#pragma unroll
  for (int kc = 0; kc < 4; kc++)
    aq[kc] = *(const short8*)&qp_sm[(wave * 16 + l16) * 136 + kc * 32 + quad * 8];

  float m_i = -1e30f, l_i = 0.f;
  f32x4 zero4 = {0.f, 0.f, 0.f, 0.f};
  f32x4 o_acc[8];  // o_acc[dt][r] = O[d = dt*16+quad*4+r][q = l16]
#pragma unroll
  for (int dt = 0; dt < 8; dt++) o_acc[dt] = zero4;

  const u16* Kbase = Kc + ((size_t)(b * 8 + kvh)) * KVLEN_ * 128;
  const u16* Vbase = Vt + ((size_t)(b * 8 + kvh)) * 128 * KVLEN_;
  const int qlo = PREV_ + qb * 64;
  const int qpos = qlo + wave * 16 + l16;  // this lane's q row
  const int ntiles = (qlo + 63) / 64 + 1;
  u16* prow = &qp_sm[(wave * 16 + l16) * 136];  // wave-private P^T row (q = l16)

  for (int t = 0; t < ntiles; t++) {
    const int kb = t * 64;
    __syncthreads();
#pragma unroll
    for (int i = 0; i < 4; i++) {
      int c = tid + i * 256;
      {
        int r = c >> 4, col = (c & 15) * 8;
        *(short8*)&k_sm[r * 136 + col] = *(const short8*)&Kbase[(size_t)(kb + r) * 128 + col];
      }
      {
        int d = c >> 3, kcol = (c & 7) * 8;
        *(short8*)&v_sm[d * 72 + kcol] = *(const short8*)&Vbase[(size_t)d * KVLEN_ + kb + kcol];
      }
    }
    __syncthreads();
    // S^T: rows kv (quad*4+r within nt tile), col q = l16
    f32x4 s[4];
    __builtin_amdgcn_s_setprio(1);
#pragma unroll
    for (int nt = 0; nt < 4; nt++) {
      f32x4 acc = zero4;
#pragma unroll
      for (int kc = 0; kc < 4; kc++) {
        short8 bk = *(const short8*)&k_sm[(nt * 16 + l16) * 136 + kc * 32 + quad * 8];
        acc = __builtin_amdgcn_mfma_f32_16x16x32_bf16(bk, aq[kc], acc, 0, 0, 0);
      }
      s[nt] = acc;
    }
    __builtin_amdgcn_s_setprio(0);
    if (kb + 63 > qlo + wave * 16 || kb + 63 >= TOTLEN_) {
#pragma unroll
      for (int nt = 0; nt < 4; nt++)
#pragma unroll
        for (int r = 0; r < 4; r++) {
          int kv = kb + nt * 16 + quad * 4 + r;
          if (kv > qpos || kv >= TOTLEN_) s[nt][r] = -1e30f;
        }
    }
    // lane-local max over 16 values, then reduce across quad (lane bits 4,5)
    float cur = fmaxf(fmaxf(fmaxf(s[0][0], s[0][1]), fmaxf(s[0][2], s[0][3])),
                      fmaxf(fmaxf(s[1][0], s[1][1]), fmaxf(s[1][2], s[1][3])));
    cur = fmaxf(cur, fmaxf(fmaxf(fmaxf(s[2][0], s[2][1]), fmaxf(s[2][2], s[2][3])),
                           fmaxf(fmaxf(s[3][0], s[3][1]), fmaxf(s[3][2], s[3][3]))));
    cur = fmaxf(cur, __shfl_xor(cur, 16, 64));
    cur = fmaxf(cur, __shfl_xor(cur, 32, 64));
    if (!__all(cur <= m_i)) {  // defer-max: skip rescale when max didn't grow (exact)
      float mn = fmaxf(m_i, cur);
      float alpha = __expf(m_i - mn);
      m_i = mn;
      l_i *= alpha;
#pragma unroll
      for (int dt = 0; dt < 8; dt++)
#pragma unroll
        for (int r = 0; r < 4; r++) o_acc[dt][r] *= alpha;
    }
    float psum = 0.f;
    unsigned pk0[4], pk1[4];
#pragma unroll
    for (int nt = 0; nt < 4; nt++) {
      float e0 = __expf(s[nt][0] - m_i);
      float e1 = __expf(s[nt][1] - m_i);
      float e2 = __expf(s[nt][2] - m_i);
      float e3 = __expf(s[nt][3] - m_i);
      psum += (e0 + e1) + (e2 + e3);
      pk0[nt] = cvt_pk_bf16(e0, e1);
      pk1[nt] = cvt_pk_bf16(e2, e3);
    }
    l_i += psum;  // per-lane partial; reduced once after the loop
    // write P^T into wave-private row: kv = nt*16 + quad*4 + {0..3}
#pragma unroll
    for (int nt = 0; nt < 4; nt++) {
      uint2 t2;
      t2.x = pk0[nt];
      t2.y = pk1[nt];
      *(uint2*)&prow[nt * 16 + quad * 4] = t2;
    }
    // PV: O^T += V^T * P^T (same-wave LDS dep; compiler inserts lgkmcnt)
    __builtin_amdgcn_s_setprio(1);
#pragma unroll
    for (int kc = 0; kc < 2; kc++) {
      short8 pfrag = *(const short8*)&prow[kc * 32 + quad * 8];
#pragma unroll
      for (int dt = 0; dt < 8; dt++) {
        short8 av = *(const short8*)&v_sm[(dt * 16 + l16) * 72 + kc * 32 + quad * 8];
        o_acc[dt] = __builtin_amdgcn_mfma_f32_16x16x32_bf16(av, pfrag, o_acc[dt], 0, 0, 0);
      }
    }
    __builtin_amdgcn_s_setprio(0);
  }
  l_i += __shfl_xor(l_i, 16, 64);
  l_i += __shfl_xor(l_i, 32, 64);
  float invl = 1.f / l_i;
  __syncthreads();  // all waves done reading k_sm; reuse as O-transpose scratch
  u16* orow = &k_sm[(wave * 16 + l16) * 136];
#pragma unroll
  for (int dt = 0; dt < 8; dt++) {
    uint2 t2;
    t2.x = cvt_pk_bf16(o_acc[dt][0] * invl, o_acc[dt][1] * invl);
    t2.y = cvt_pk_bf16(o_acc[dt][2] * invl, o_acc[dt][3] * invl);
    *(uint2*)&orow[dt * 16 + quad * 4] = t2;
  }
  // wave-private readback: row-major store to Obuf
  int rr = lane >> 2, cc = lane & 3;
  const u16* srow = &k_sm[(wave * 16 + rr) * 136];
  size_t gbase = ((size_t)(b * 512 + qb * 64 + wave * 16 + rr)) * 4096 + (size_t)h * 128;
#pragma unroll
  for (int i = 0; i < 4; i++) {
    int col = (cc + i * 4) * 8;
    *(short8*)&Obuf[gbase + col] = *(const short8*)&srow[col];
  }
}

extern "C" void kernel_launch(void* const* d_in, const int* in_sizes, int n_in,
                              void* d_out, int out_size, void* d_ws, size_t ws_size,
                              hipStream_t stream) {
  const float* hidden = (const float*)d_in[0];
  const float* paged = (const float*)d_in[1];
  const float* Wq = (const float*)d_in[2];
  const float* Wk = (const float*)d_in[3];
  const float* Wv = (const float*)d_in[4];
  const float* Wo = (const float*)d_in[5];
  const int* kv_indptr = (const int*)d_in[7];
  const int* kv_indices = (const int*)d_in[8];

  float* out = (float*)d_out;
  float* out_paged = out + (size_t)B_ * QLEN_ * HID_;                               // 8,388,608
  float* out_ints = out_paged + (size_t)MAXP_ * 2 * 16 * NKV_ * HD_;                // +67,108,864

  char* w = (char*)d_ws;
  u16* hid_bf = (u16*)(w + 0);
  u16* wq_bf = (u16*)(w + 16777216);
  u16* wk_bf = (u16*)(w + 50331648);   // wk_bf and wv_bf adjacent -> one N=2048 GEMM B
  u16* wv_bf = (u16*)(w + 58720256);
  u16* wo_bf = (u16*)(w + 67108864);
  float* q_f32 = (float*)(w + 100663296);
  float* kv_f32 = (float*)(w + 134217728);  // [2048 tok][2048]: K cols 0-1023, V cols 1024-2047
  u16* kc = (u16*)(w + 167772160);
  u16* vt = (u16*)(w + 180355072);
  u16* obuf = (u16*)(w + 192937984);
  int* aps = (int*)(w + 209715200);

  hipMemcpyAsync(out_paged, paged, (size_t)MAXP_ * 2 * 16 * NKV_ * HD_ * 4,
                 hipMemcpyDeviceToDevice, stream);
  page_setup<<<1, 256, 0, stream>>>(kv_indptr, kv_indices, out_ints, aps);

  conv_bf16<<<4096, 256, 0, stream>>>(hidden, hid_bf, 8388608 / 8);
  conv_bf16<<<8192, 256, 0, stream>>>(Wq, wq_bf, 16777216 / 8);
  conv_bf16<<<2048, 256, 0, stream>>>(Wk, wk_bf, 4194304 / 8);
  conv_bf16<<<2048, 256, 0, stream>>>(Wv, wv_bf, 4194304 / 8);
  conv_bf16<<<8192, 256, 0, stream>>>(Wo, wo_bf, 16777216 / 8);

  gemm_bt<<<dim3(32, 16), 256, 0, stream>>>(hid_bf, wq_bf, q_f32, 2048, 4096, 4096);
  gemm_bt<<<dim3(16, 16), 256, 0, stream>>>(hid_bf, wk_bf, kv_f32, 2048, 2048, 4096);  // K+V fused

  scatter_kv<<<4096, 256, 0, stream>>>(kv_f32, aps, out_paged);
  build_kc<<<12288, 256, 0, stream>>>(paged, kv_f32, kv_indices, kc);
  build_vt<<<768, 256, 0, stream>>>(paged, kv_f32, kv_indices, vt);

  flash_attn<<<dim3(8, 32, 4), 256, 0, stream>>>(q_f32, kc, vt, obuf);  // RoPE-Q fused in prologue

  gemm_bt<<<dim3(32, 16), 256, 0, stream>>>(obuf, wo_bf, out, 2048, 4096, 4096);
}